// Round 6
// baseline (48.992 us; speedup 1.0000x reference)
//
#include <hip/hip_runtime.h>

// LIF "RepeatEncoder": input (B,L,C) f32, output spikes (T,B,C,L) f32.
// v=0; per t: v = v + (a - v)*0.5; s = (v >= 1); v = s ? 0 : v; out[t,b,c,l] = s.
// Input is time-constant, so each thread runs the 16-step recurrence privately.
//
// Round-6: store-stream contiguity. Block = 8 c-rows x 512 l of one b.
// Each wave owns 2 full c-rows; per t-step it stores a contiguous 4KB run
// (block: 16KB contiguous per plane) instead of 128B runs at 2KB stride ->
// DRAM page-hit rate approaches memset's sequential pattern.
// Plain (cached) stores — round 5 proved nt costs ~10%.

#define T_STEPS 16
#define B 64
#define L 512
#define C 128
#define CT 8            // c-rows per block
#define LDS_STRIDE 516  // 512 + 4: keeps b128 reads 16B-aligned, ds_write <=2-way

typedef float v4f __attribute__((ext_vector_type(4)));

__global__ __launch_bounds__(256, 4) void lif_repeat_kernel(const float* __restrict__ in,
                                                            float* __restrict__ out) {
    __shared__ float lds[CT][LDS_STRIDE];   // 16.5 KB

    const int blk = blockIdx.x;             // 1024 blocks
    const int c0  = (blk & 15) * CT;        // 16 c-groups
    const int b   = blk >> 4;               // 64 b
    const int tid = threadIdx.x;
    const int w    = tid >> 6;              // wave 0..3
    const int lane = tid & 63;

    // Cooperative load of in[b, 0..511, c0..c0+7], transposed into LDS[cc][l].
    const float* inb = in + (size_t)b * L * C + c0;
#pragma unroll
    for (int k = 0; k < 16; ++k) {
        const int e  = tid + 256 * k;       // 0..4095
        const int r  = e >> 3;              // l-row 0..511
        const int cc = e & 7;               // c    0..7
        lds[cc][r] = inb[(size_t)r * C + cc];
    }
    __syncthreads();

    // Thread owns 4 elems in each of (2 c-rows) x (2 l-halves):
    // c = c0 + w*2 + cr ; l = h*256 + lane*4 + j.
    float a[2][2][4], v[2][2][4];
#pragma unroll
    for (int cr = 0; cr < 2; ++cr)
#pragma unroll
        for (int h = 0; h < 2; ++h) {
            const v4f t4 = *reinterpret_cast<const v4f*>(&lds[w * 2 + cr][h * 256 + lane * 4]);
            a[cr][h][0] = t4.x; a[cr][h][1] = t4.y; a[cr][h][2] = t4.z; a[cr][h][3] = t4.w;
            v[cr][h][0] = 0.f;  v[cr][h][1] = 0.f;  v[cr][h][2] = 0.f;  v[cr][h][3] = 0.f;
        }

    // Wave w's 4 stores per t tile [w*4KB, (w+1)*4KB) of the block's 16KB run.
    float* outp = out + ((size_t)(b * C + c0 + w * 2)) * L + lane * 4;
    const size_t plane = (size_t)B * C * L;

#pragma unroll
    for (int t = 0; t < T_STEPS; ++t) {
        float* pt = outp + (size_t)t * plane;
#pragma unroll
        for (int cr = 0; cr < 2; ++cr)
#pragma unroll
            for (int h = 0; h < 2; ++h) {
                float s[4];
#pragma unroll
                for (int j = 0; j < 4; ++j) {
                    // Exact replication of reference arithmetic: v = v + (x - v)/2.
                    // (x-v)*0.5 is exact; FMA contraction cannot change bits.
                    float vv = v[cr][h][j];
                    vv = vv + (a[cr][h][j] - vv) * 0.5f;
                    s[j] = (vv >= 1.0f) ? 1.0f : 0.0f;
                    v[cr][h][j] = (s[j] != 0.0f) ? 0.0f : vv;
                }
                *reinterpret_cast<v4f*>(pt + cr * L + h * 256) = (v4f){s[0], s[1], s[2], s[3]};
            }
    }
}

extern "C" void kernel_launch(void* const* d_in, const int* in_sizes, int n_in,
                              void* d_out, int out_size, void* d_ws, size_t ws_size,
                              hipStream_t stream) {
    const float* in = (const float*)d_in[0];
    float* out = (float*)d_out;

    const int grid = B * (C / CT);          // 64*16 = 1024
    hipLaunchKernelGGL(lif_repeat_kernel, dim3(grid), dim3(256), 0, stream, in, out);
}